// Round 9
// baseline (3857.994 us; speedup 1.0000x reference)
//
#include <hip/hip_runtime.h>

#define NB 256      // batch
#define NT 512      // time steps
#define NH 1024     // hidden
#define BH (NB * NH)
#define GRID_WGS 256
#define BLOCK 512

typedef __attribute__((ext_vector_type(8))) __bf16 bfrag;
typedef __attribute__((ext_vector_type(4))) float f32x4;
typedef __attribute__((ext_vector_type(4))) unsigned u32x4;
typedef __attribute__((ext_vector_type(8))) unsigned short u16x8;
typedef unsigned short us;

// h1(t) in buf[(t+3)%3]; h2(t) in buf[t&3]  (skew<=1 proof-safe)
__device__ __attribute__((aligned(16))) us g_h1[3 * BH];
__device__ __attribute__((aligned(16))) us g_h2[4 * BH];
// split monotonic flags (never reset -> graph-replay safe); one 128B line/group
__device__ __attribute__((aligned(128))) unsigned g_flagA[GRID_WGS];
__device__ __attribute__((aligned(128))) unsigned g_flagB[GRID_WGS];

__device__ __forceinline__ us f2bf(float f) {
  union { float f; unsigned u; } v; v.f = f;
  unsigned r = v.u + 0x7FFFu + ((v.u >> 16) & 1u);  // RTE
  return (us)(r >> 16);
}
__device__ __forceinline__ float bf2f(us u) {
  union { unsigned u; float f; } v; v.u = ((unsigned)u) << 16;
  return v.f;
}

__device__ __forceinline__ bfrag cvt8(const float* __restrict__ p) {
  f32x4 a = *reinterpret_cast<const f32x4*>(p);
  f32x4 b = *reinterpret_cast<const f32x4*>(p + 4);
  u16x8 u;
#pragma unroll
  for (int i = 0; i < 4; ++i) { u[i] = f2bf(a[i]); u[i + 4] = f2bf(b[i]); }
  union { u16x8 u; bfrag b; } c; c.u = u; return c.b;
}

// ---- device-coherent (sc0 sc1 -> L3 coherence point) ops
union f16u { u32x4 v; bfrag b; u16x8 s; };
__device__ __forceinline__ u32x4 ld16_dev(const void* p) {
  u32x4 r;
  asm volatile("global_load_dwordx4 %0, %1, off sc0 sc1" : "=v"(r) : "v"(p));
  return r;   // caller must s_waitcnt before use
}
__device__ __forceinline__ unsigned ld4_dev(const void* p) {
  unsigned r;
  asm volatile("global_load_dword %0, %1, off sc0 sc1\n\ts_waitcnt vmcnt(0)"
               : "=v"(r) : "v"(p) : "memory");
  return r;
}
__device__ __forceinline__ void st4_dev(void* p, unsigned v) {
  asm volatile("global_store_dword %0, %1, off sc0 sc1" :: "v"(p), "v"(v) : "memory");
}

// poll 4 flags with lanes 0..3 only (cuts L3 polling traffic 16x vs 64-lane)
__device__ __forceinline__ void wait4(const unsigned* f, int lane, unsigned tgt) {
  unsigned v = tgt;
  for (;;) {
    if (lane < 4) v = ld4_dev(f + lane);
    if (!__any((int)(v < tgt))) break;
    __builtin_amdgcn_s_sleep(1);
  }
}
__device__ __forceinline__ void wait32(const unsigned* f, int lane, unsigned tgt) {
  unsigned v = tgt;
  for (;;) {
    if (lane < 32) v = ld4_dev(f + lane);
    if (!__any((int)(v < tgt))) break;
    __builtin_amdgcn_s_sleep(1);
  }
}

// out(t)[r_g, c=w] = dot(h2(t)[r_g,:], Wlin[w,:]) + blin[w]; waves 0,1
__device__ __forceinline__ void out_row(const us* h2, int r_g, int w, int lane,
                                        const float* __restrict__ Wlin,
                                        const float* __restrict__ blin,
                                        float* __restrict__ out, int t) {
  const us* hp = h2 + r_g * NH + lane * 16;
  const float* wl = Wlin + w * NH + lane * 16;
  f16u h0, h1v;
  h0.v  = ld16_dev(hp);
  h1v.v = ld16_dev(hp + 8);
  asm volatile("s_waitcnt vmcnt(0)" ::: "memory");
  __builtin_amdgcn_sched_barrier(0);
  float s = 0.f;
#pragma unroll
  for (int e = 0; e < 8; ++e) {
    s = fmaf(bf2f(h0.s[e]),  wl[e],     s);
    s = fmaf(bf2f(h1v.s[e]), wl[8 + e], s);
  }
#pragma unroll
  for (int m = 1; m < 64; m <<= 1) s += __shfl_xor(s, m);
  if (lane == 0) out[r_g * (2 * NT) + w * NT + t] = s + blin[w];
}

#define MFMA(a, b, c) __builtin_amdgcn_mfma_f32_16x16x32_bf16((a), (b), (c), 0, 0, 0)

__global__ void __launch_bounds__(BLOCK, 1) rnn_kernel(
    const float* __restrict__ x,     // [B][2][T]
    const float* __restrict__ Wi1,   // [H][2]
    const float* __restrict__ Whh1,  // [H][H]
    const float* __restrict__ Wih2,  // [H][H]
    const float* __restrict__ Whh2,  // [H][H]
    const float* __restrict__ bih1,
    const float* __restrict__ bhh1,
    const float* __restrict__ bih2,
    const float* __restrict__ bhh2,
    const float* __restrict__ Wlin,  // [2][H]
    const float* __restrict__ blin,  // [2]
    float* __restrict__ out)         // [B][2][T]
{
  const int bid = blockIdx.x, tid = threadIdx.x;
  const int w = tid >> 6, lane = tid & 63;
  const int mb = bid >> 5, nb = bid & 31;  // group mb rows [mb*32,+32); slot nb cols [nb*32,+32)
  unsigned* gfA = g_flagA + mb * 32;
  unsigned* gfB = g_flagB + mb * 32;

  // my own flags only advance when I store them -> stable base samples
  const unsigned fbA = ld4_dev(&gfA[nb]);
  const unsigned fbB = ld4_dev(&gfB[nb]);

  // zero t<0 buffers: h1(-1)=buf2, h2(-2)=buf2, h2(-1)=buf3 (my 32x32 tile)
  {
    const int zrow = tid >> 4, zc = tid & 15;
    const int off_d = ((mb * 32 + zrow) * NH + nb * 32) / 2;
    st4_dev((unsigned*)(g_h1 + 2 * BH) + off_d + zc, 0u);
    st4_dev((unsigned*)(g_h2 + 2 * BH) + off_d + zc, 0u);
    st4_dev((unsigned*)(g_h2 + 3 * BH) + off_d + zc, 0u);
  }

  // ---- persistent weight fragments: wave w owns K-slice [w*128,+128), 32 cols
  const int fr = lane & 15;
  const int ko = (lane >> 4) << 3;        // 0,8,16,24
  const int kbase = w * 128;
  bfrag w1[2][4], w2i[2][4], w2h[2][4];   // [col-half cf][k-step st]
#pragma unroll
  for (int cf = 0; cf < 2; ++cf)
#pragma unroll
    for (int st = 0; st < 4; ++st) {
      const int off = (nb * 32 + cf * 16 + fr) * NH + kbase + st * 32 + ko;
      w1[cf][st]  = cvt8(Whh1 + off);
      w2i[cf][st] = cvt8(Wih2 + off);
      w2h[cf][st] = cvt8(Whh2 + off);
    }

  // ---- per-thread epilogue constants (2 adjacent cols of one row)
  const int rl = tid >> 4, cl = (tid & 15) * 2;
  const int grow = mb * 32 + rl, gcol = nb * 32 + cl;
  const float b1s0 = bih1[gcol] + bhh1[gcol];
  const float b1s1 = bih1[gcol + 1] + bhh1[gcol + 1];
  const float b2s0 = bih2[gcol] + bhh2[gcol];
  const float b2s1 = bih2[gcol + 1] + bhh2[gcol + 1];
  const float wi00 = Wi1[gcol * 2],       wi01 = Wi1[gcol * 2 + 1];
  const float wi10 = Wi1[(gcol + 1) * 2], wi11 = Wi1[(gcol + 1) * 2 + 1];
  const float* xrow = x + grow * (2 * NT);

  __shared__ float redA[8][32][36];
  __shared__ float redB[8][32][36];

  const int arow0 = mb * 32 + fr;     // A-frag row base (+ mf*16)
  const int prow = (lane >> 4) << 2;  // C/D row base within 16x16 frag
  const int r_g = bid;                // this WG's out row

  // preamble complete (zeros + weights) -> publish both bases+1
  asm volatile("s_waitcnt vmcnt(0)" ::: "memory");
  __syncthreads();
  if (tid == 0) { st4_dev(&gfA[nb], fbA + 1u); st4_dev(&gfB[nb], fbB + 1u); }

  for (int p = 0; p <= NT; ++p) {
    const us* h1_prev = g_h1 + ((p + 2) % 3) * BH;   // h1(p-1)
    us*       h1_cur  = g_h1 + (p % 3) * BH;         // h1(p)
    const us* h2_pp   = g_h2 + ((p + 2) & 3) * BH;   // h2(p-2)
    us*       h2_cur  = g_h2 + ((p + 3) & 3) * BH;   // h2(p-1)
    const us* h2_out  = g_h2 + ((p + 1) & 3) * BH;   // h2(p-3)

    // ================= A chain (critical): h1(p) = tanh(h1(p-1)W1^T + x + b)
    wait4(gfA + w * 4, lane, fbA + 1u + (unsigned)p);
    __builtin_amdgcn_sched_barrier(0);

    const float x0 = xrow[p < NT ? p : 0], x1 = xrow[NT + (p < NT ? p : 0)];

    f16u a1[2][4];
    {
      const us* pa = h1_prev + arow0 * NH + kbase + ko;
      const us* pb = h1_prev + (arow0 + 16) * NH + kbase + ko;
#pragma unroll
      for (int st = 0; st < 4; ++st) a1[0][st].v = ld16_dev(pa + st * 32);
#pragma unroll
      for (int st = 0; st < 4; ++st) a1[1][st].v = ld16_dev(pb + st * 32);
    }
    f32x4 accA[2][2] = {};
    asm volatile("s_waitcnt vmcnt(4)" ::: "memory");   // a1[0] ready
    __builtin_amdgcn_sched_barrier(0);
#pragma unroll
    for (int st = 0; st < 4; ++st) {
      accA[0][0] = MFMA(a1[0][st].b, w1[0][st], accA[0][0]);
      accA[0][1] = MFMA(a1[0][st].b, w1[1][st], accA[0][1]);
    }
    asm volatile("s_waitcnt vmcnt(0)" ::: "memory");   // a1[1] ready
    __builtin_amdgcn_sched_barrier(0);
#pragma unroll
    for (int st = 0; st < 4; ++st) {
      accA[1][0] = MFMA(a1[1][st].b, w1[0][st], accA[1][0]);
      accA[1][1] = MFMA(a1[1][st].b, w1[1][st], accA[1][1]);
    }
#pragma unroll
    for (int mf = 0; mf < 2; ++mf)
#pragma unroll
      for (int cf = 0; cf < 2; ++cf)
#pragma unroll
        for (int r = 0; r < 4; ++r)
          redA[w][mf * 16 + prow + r][cf * 16 + fr] = accA[mf][cf][r];
    __syncthreads();   // also establishes: ALL 32 slots have fA >= fbA+1+p

    if (p < NT) {
      float sA0 = 0.f, sA1 = 0.f;
#pragma unroll
      for (int u = 0; u < 8; ++u) {
        const float2 a = *reinterpret_cast<const float2*>(&redA[u][rl][cl]);
        sA0 += a.x; sA1 += a.y;
      }
      const float v0 = sA0 + b1s0 + x0 * wi00 + x1 * wi01;
      const float v1 = sA1 + b1s1 + x0 * wi10 + x1 * wi11;
      st4_dev(h1_cur + grow * NH + gcol,
              (unsigned)f2bf(tanhf(v0)) | ((unsigned)f2bf(tanhf(v1)) << 16));
    }
    asm volatile("s_waitcnt vmcnt(0)" ::: "memory");   // h1 store acked
    __syncthreads();
    if (tid == 0) st4_dev(&gfA[nb], fbA + 2u + (unsigned)p);

    // out(p-3): safe (post-A-sync all-32 property => h2(p-3) stored; quad buf)
    if (p >= 3 && w < 2)
      out_row(h2_out, r_g, w, lane, Wlin, blin, out, p - 3);

    // ================= B chain: h2(p-1) = tanh(h1(p-1)W2i^T + h2(p-2)W2h^T + b)
    if (p >= 2) wait4(gfB + w * 4, lane, fbB + (unsigned)p);
    __builtin_amdgcn_sched_barrier(0);

    f16u a2[2][4];
    {
      const us* pa = h2_pp + arow0 * NH + kbase + ko;
      const us* pb = h2_pp + (arow0 + 16) * NH + kbase + ko;
#pragma unroll
      for (int st = 0; st < 4; ++st) a2[0][st].v = ld16_dev(pa + st * 32);
#pragma unroll
      for (int st = 0; st < 4; ++st) a2[1][st].v = ld16_dev(pb + st * 32);
    }
    f32x4 accB[2][2] = {};
    asm volatile("s_waitcnt vmcnt(4)" ::: "memory");   // a2[0] ready
    __builtin_amdgcn_sched_barrier(0);
#pragma unroll
    for (int st = 0; st < 4; ++st) {
      accB[0][0] = MFMA(a1[0][st].b, w2i[0][st], accB[0][0]);  // a1 reg reuse
      accB[0][1] = MFMA(a1[0][st].b, w2i[1][st], accB[0][1]);
      accB[0][0] = MFMA(a2[0][st].b, w2h[0][st], accB[0][0]);
      accB[0][1] = MFMA(a2[0][st].b, w2h[1][st], accB[0][1]);
    }
    asm volatile("s_waitcnt vmcnt(0)" ::: "memory");   // a2[1] ready
    __builtin_amdgcn_sched_barrier(0);
#pragma unroll
    for (int st = 0; st < 4; ++st) {
      accB[1][0] = MFMA(a1[1][st].b, w2i[0][st], accB[1][0]);
      accB[1][1] = MFMA(a1[1][st].b, w2i[1][st], accB[1][1]);
      accB[1][0] = MFMA(a2[1][st].b, w2h[0][st], accB[1][0]);
      accB[1][1] = MFMA(a2[1][st].b, w2h[1][st], accB[1][1]);
    }
#pragma unroll
    for (int mf = 0; mf < 2; ++mf)
#pragma unroll
      for (int cf = 0; cf < 2; ++cf)
#pragma unroll
        for (int r = 0; r < 4; ++r)
          redB[w][mf * 16 + prow + r][cf * 16 + fr] = accB[mf][cf][r];
    __syncthreads();

    if (p >= 1) {
      float sB0 = 0.f, sB1 = 0.f;
#pragma unroll
      for (int u = 0; u < 8; ++u) {
        const float2 b = *reinterpret_cast<const float2*>(&redB[u][rl][cl]);
        sB0 += b.x; sB1 += b.y;
      }
      const float v0 = sB0 + b2s0;
      const float v1 = sB1 + b2s1;
      st4_dev(h2_cur + grow * NH + gcol,
              (unsigned)f2bf(tanhf(v0)) | ((unsigned)f2bf(tanhf(v1)) << 16));
    }
    asm volatile("s_waitcnt vmcnt(0)" ::: "memory");   // h2 store acked
    __syncthreads();
    if (tid == 0) st4_dev(&gfB[nb], fbB + 1u + (unsigned)p);
  }

  // tail: out(NT-2), out(NT-1) need all slots' h2 through t=NT-1
  wait32(gfB, lane, fbB + 1u + (unsigned)NT);
  if (w < 2) {
    out_row(g_h2 + ((NT - 2) & 3) * BH, r_g, w, lane, Wlin, blin, out, NT - 2);
    out_row(g_h2 + ((NT - 1) & 3) * BH, r_g, w, lane, Wlin, blin, out, NT - 1);
  }
}

extern "C" void kernel_launch(void* const* d_in, const int* in_sizes, int n_in,
                              void* d_out, int out_size, void* d_ws, size_t ws_size,
                              hipStream_t stream) {
  (void)in_sizes; (void)n_in; (void)d_ws; (void)ws_size; (void)out_size;
  const float* x    = (const float*)d_in[0];
  const float* Wi1  = (const float*)d_in[1];
  const float* Whh1 = (const float*)d_in[2];
  const float* bih1 = (const float*)d_in[3];
  const float* bhh1 = (const float*)d_in[4];
  const float* Wih2 = (const float*)d_in[5];
  const float* Whh2 = (const float*)d_in[6];
  const float* bih2 = (const float*)d_in[7];
  const float* bhh2 = (const float*)d_in[8];
  const float* Wlin = (const float*)d_in[9];
  const float* blin = (const float*)d_in[10];
  float* out = (float*)d_out;

  void* args[] = { (void*)&x, (void*)&Wi1, (void*)&Whh1, (void*)&Wih2, (void*)&Whh2,
                   (void*)&bih1, (void*)&bhh1, (void*)&bih2, (void*)&bhh2,
                   (void*)&Wlin, (void*)&blin, (void*)&out };
  hipLaunchCooperativeKernel((void*)rnn_kernel, dim3(GRID_WGS), dim3(BLOCK),
                             args, 0, stream);
}